// Round 3
// baseline (357.441 us; speedup 1.0000x reference)
//
#include <hip/hip_runtime.h>
#include <hip/hip_bf16.h>
#include <stdint.h>

// Problem constants
#define BB   4
#define SS   2048
#define DIN  1024
#define DOUT 1024
#define NH   16
#define HD   64
#define MROWS (BB * SS)   // 8192

typedef __bf16 bf16x8 __attribute__((ext_vector_type(8)));
typedef float  f32x4  __attribute__((ext_vector_type(4)));

__device__ __forceinline__ unsigned short f2bf(float f) {
  union { float f; uint32_t u; } v; v.f = f;
  uint32_t u = v.u;
  uint32_t r = (u + 0x7fffu + ((u >> 16) & 1u)) >> 16;
  return (unsigned short)r;
}

// v_cvt_pk_bf16_f32: lo -> low16, hi -> high16 (RNE)
__device__ __forceinline__ unsigned int cvt_pk_bf16(float lo, float hi) {
  unsigned int r;
  asm("v_cvt_pk_bf16_f32 %0, %1, %2" : "=v"(r) : "v"(lo), "v"(hi));
  return r;
}

#define GLOAD_LDS16(gsrc, ldst)                                                   \
  __builtin_amdgcn_global_load_lds(                                               \
      (const __attribute__((address_space(1))) void*)(gsrc),                      \
      (__attribute__((address_space(3))) void*)(ldst), 16, 0, 0)

// ---------------- conversion kernels ----------------

__global__ void cvt_x_kernel(const float* __restrict__ in,
                             unsigned short* __restrict__ out, int n4) {
  int i = blockIdx.x * blockDim.x + threadIdx.x;
  int stride = gridDim.x * blockDim.x;
  for (; i < n4; i += stride) {
    float4 f = ((const float4*)in)[i];
    ushort4 o;
    o.x = f2bf(f.x); o.y = f2bf(f.y); o.z = f2bf(f.z); o.w = f2bf(f.w);
    ((ushort4*)out)[i] = o;
  }
}

// transpose-convert: out[n][k] = bf16(W[k][n]), per blockIdx.z matrix
__global__ void cvt_w_t_kernel(const float* __restrict__ w0,
                               const float* __restrict__ w1,
                               const float* __restrict__ w2,
                               const float* __restrict__ w3,
                               unsigned short* __restrict__ out) {
  __shared__ float tile[32][33];
  const float* src = (blockIdx.z == 0) ? w0 : (blockIdx.z == 1) ? w1
                   : (blockIdx.z == 2) ? w2 : w3;
  unsigned short* dst = out + (size_t)blockIdx.z * (DIN * DOUT);
  int kb = blockIdx.x * 32, nb = blockIdx.y * 32;
  tile[threadIdx.y][threadIdx.x] = src[(size_t)(kb + threadIdx.y) * DOUT + nb + threadIdx.x];
  __syncthreads();
  dst[(size_t)(nb + threadIdx.y) * DIN + kb + threadIdx.x] = f2bf(tile[threadIdx.x][threadIdx.y]);
}

// ---------------- GEMM core: 128x128 tile, 4 waves, global_load_lds (m97) ----
__device__ __forceinline__ void gemm_core(const unsigned short* __restrict__ A,
                                          const unsigned short* __restrict__ BT,
                                          f32x4 (&acc)[4][4]) {
  const int tid  = threadIdx.x;
  const int lane = tid & 63;
  const int wave = tid >> 6;
  const int wm = (wave >> 1) * 64, wn = (wave & 1) * 64;
  const int g = lane >> 4, c = lane & 15;

  __shared__ __align__(16) unsigned short As[128 * 32];
  __shared__ __align__(16) unsigned short Bs[128 * 32];

#pragma unroll
  for (int mi = 0; mi < 4; mi++)
#pragma unroll
    for (int ni = 0; ni < 4; ni++)
      acc[mi][ni] = (f32x4){0.f, 0.f, 0.f, 0.f};

  const int rj0 = (0 * 4 + wave) * 16 + (lane >> 2);
  const int rj1 = (1 * 4 + wave) * 16 + (lane >> 2);
  const int gcol = (lane & 3) * 8;
  const unsigned short* Ag0 = A + (size_t)rj0 * 1024 + gcol;
  const unsigned short* Ag1 = A + (size_t)rj1 * 1024 + gcol;
  const unsigned short* Bg0 = BT + (size_t)rj0 * 1024 + gcol;
  const unsigned short* Bg1 = BT + (size_t)rj1 * 1024 + gcol;
  unsigned short* As0 = &As[(0 * 4 + wave) * 512 + lane * 8];
  unsigned short* As1 = &As[(1 * 4 + wave) * 512 + lane * 8];
  unsigned short* Bs0 = &Bs[(0 * 4 + wave) * 512 + lane * 8];
  unsigned short* Bs1 = &Bs[(1 * 4 + wave) * 512 + lane * 8];

  for (int k0 = 0; k0 < 1024; k0 += 32) {
    __syncthreads();
    GLOAD_LDS16(Ag0 + k0, As0);
    GLOAD_LDS16(Ag1 + k0, As1);
    GLOAD_LDS16(Bg0 + k0, Bs0);
    GLOAD_LDS16(Bg1 + k0, Bs1);
    __syncthreads();
    bf16x8 a[4], b[4];
#pragma unroll
    for (int mi = 0; mi < 4; mi++)
      a[mi] = *(const bf16x8*)&As[(wm + mi * 16 + c) * 32 + g * 8];
#pragma unroll
    for (int ni = 0; ni < 4; ni++)
      b[ni] = *(const bf16x8*)&Bs[(wn + ni * 16 + c) * 32 + g * 8];
#pragma unroll
    for (int mi = 0; mi < 4; mi++)
#pragma unroll
      for (int ni = 0; ni < 4; ni++)
        acc[mi][ni] = __builtin_amdgcn_mfma_f32_16x16x32_bf16(a[mi], b[ni], acc[mi][ni], 0, 0, 0);
  }
}

// QKV projection. z=0: Q (scaled log2e/8) -> [b][h][s][hd]; z=1: K; z=2: V^T [b][h][hd][s]
__global__ __launch_bounds__(256) void gemm_qkv_kernel(
    const unsigned short* __restrict__ xb, const unsigned short* __restrict__ wt,
    unsigned short* __restrict__ qs, unsigned short* __restrict__ kbuf,
    unsigned short* __restrict__ vt) {
  const int nT = blockIdx.x, mT = blockIdx.y, z = blockIdx.z;
  f32x4 acc[4][4];
  gemm_core(xb + (size_t)mT * 128 * 1024,
            wt + (size_t)z * (DIN * DOUT) + (size_t)nT * 128 * 1024, acc);

  const int tid = threadIdx.x, lane = tid & 63, wave = tid >> 6;
  const int wm = (wave >> 1) * 64, wn = (wave & 1) * 64;
  const int g = lane >> 4, c = lane & 15;
  // Q folded scale: (1/sqrt(HD)) * log2(e) so attention uses exp2
  const float scale = (z == 0) ? 0.18033688011112042f : 1.0f;
  unsigned short* dstQK = (z == 0) ? qs : kbuf;
#pragma unroll
  for (int mi = 0; mi < 4; mi++)
#pragma unroll
    for (int ni = 0; ni < 4; ni++) {
      int n = nT * 128 + wn + ni * 16 + c;
      int h = n >> 6, hd = n & 63;
#pragma unroll
      for (int jj = 0; jj < 4; jj++) {
        int m = mT * 128 + wm + mi * 16 + g * 4 + jj;
        int b = m >> 11, s = m & 2047;
        unsigned short val = f2bf(acc[mi][ni][jj] * scale);
        if (z < 2)
          dstQK[(((size_t)(b * NH + h)) * SS + s) * HD + hd] = val;
        else
          vt[(((size_t)(b * NH + h)) * HD + hd) * SS + s] = val;
      }
    }
}

// Output projection: out = ctx @ Wp + bp (fp32 out)
__global__ __launch_bounds__(256) void gemm_out_kernel(
    const unsigned short* __restrict__ ctx, const unsigned short* __restrict__ wtp,
    const float* __restrict__ bp, float* __restrict__ out) {
  const int nT = blockIdx.x, mT = blockIdx.y;
  f32x4 acc[4][4];
  gemm_core(ctx + (size_t)mT * 128 * 1024, wtp + (size_t)nT * 128 * 1024, acc);

  const int tid = threadIdx.x, lane = tid & 63, wave = tid >> 6;
  const int wm = (wave >> 1) * 64, wn = (wave & 1) * 64;
  const int g = lane >> 4, c = lane & 15;
#pragma unroll
  for (int mi = 0; mi < 4; mi++)
#pragma unroll
    for (int ni = 0; ni < 4; ni++) {
      int n = nT * 128 + wn + ni * 16 + c;
      float bias = bp[n];
#pragma unroll
      for (int jj = 0; jj < 4; jj++) {
        int m = mT * 128 + wm + mi * 16 + g * 4 + jj;
        out[(size_t)m * DOUT + n] = acc[mi][ni][jj] + bias;
      }
    }
}

// ---------------- flash attention: LDS-free, all-register P ----------------
// grid: (S/128, H, B) with qt reversed (longest first); 4 waves/block; wave w
// owns 32 q rows. Swapped QK^T (lane holds P^T[.][q=c]), kv-permuted fragments
// so the P -> PV B-operand mapping is purely in-lane; PV computes ctx^T so
// softmax stats never cross lanes. K/V read directly from global (L1/L2-hot).
__global__ __launch_bounds__(256) void attn_kernel(
    const unsigned short* __restrict__ qs, const unsigned short* __restrict__ kbuf,
    const unsigned short* __restrict__ vt, unsigned short* __restrict__ ctx) {
  const int qt = (int)gridDim.x - 1 - blockIdx.x, h = blockIdx.y, b = blockIdx.z;
  const int tid = threadIdx.x, lane = tid & 63, w = tid >> 6;
  const int g = lane >> 4, c = lane & 15;
  const size_t bh = (size_t)(b * NH + h);
  const unsigned short* Q = qs + bh * SS * HD;
  const unsigned short* K = kbuf + bh * SS * HD;
  const unsigned short* V = vt + bh * HD * SS;   // [hd][s]
  const int q0w = qt * 128 + w * 32;

  // Q as B-fragments: [col=q=c][k=d]
  bf16x8 aq[2][2];
#pragma unroll
  for (int qf = 0; qf < 2; qf++)
#pragma unroll
    for (int kk = 0; kk < 2; kk++)
      aq[qf][kk] = *(const bf16x8*)&Q[(size_t)(q0w + qf * 16 + c) * HD + kk * 32 + g * 8];

  float m_run[2] = {-3.0e38f, -3.0e38f};
  float l_run[2] = {0.f, 0.f};
  f32x4 acc[2][4];   // [qf][nh]: ctx^T frag, lane holds hd = nh*16+g*4+jj for q=c
#pragma unroll
  for (int qf = 0; qf < 2; qf++)
#pragma unroll
    for (int nh = 0; nh < 4; nh++) acc[qf][nh] = (f32x4){0.f, 0.f, 0.f, 0.f};

  // K frag ni row i=c -> kv = kv0 + (c>>2)*16 + ni*4 + (c&3)  (kv-permuted)
  const unsigned short* Kbase = K + ((size_t)((c >> 2) * 16 + (c & 3))) * HD + g * 8;
  // V frag nh, k-slot kk2: kv = kv0 + 16g + 8*kk2 + j, hd = nh*16 + c
  const unsigned short* Vbase = V + (size_t)c * SS + g * 16;

  const int ntw = q0w / 64 + 1;

  for (int t = 0; t < ntw; ++t) {
    const int kv0 = t * 64;
    bf16x8 ka[4][2], va[4][2];
#pragma unroll
    for (int ni = 0; ni < 4; ni++)
#pragma unroll
      for (int kk = 0; kk < 2; kk++)
        ka[ni][kk] = *(const bf16x8*)(Kbase + (size_t)(kv0 + ni * 4) * HD + kk * 32);
#pragma unroll
    for (int nh = 0; nh < 4; nh++)
#pragma unroll
      for (int k2 = 0; k2 < 2; k2++)
        va[nh][k2] = *(const bf16x8*)(Vbase + (size_t)nh * 16 * SS + kv0 + k2 * 8);

    // S^T = K Q^T: lane (g,c) reg jj of frag ni -> P[kv0+16g+4ni+jj][q0w+qf*16+c]
    f32x4 sv[2][4];
#pragma unroll
    for (int qf = 0; qf < 2; qf++)
#pragma unroll
      for (int ni = 0; ni < 4; ni++) {
        f32x4 z = (f32x4){0.f, 0.f, 0.f, 0.f};
        z = __builtin_amdgcn_mfma_f32_16x16x32_bf16(ka[ni][0], aq[qf][0], z, 0, 0, 0);
        sv[qf][ni] = __builtin_amdgcn_mfma_f32_16x16x32_bf16(ka[ni][1], aq[qf][1], z, 0, 0, 0);
      }

    if (t == ntw - 1) {   // causal mask: only the last tile straddles the diagonal
#pragma unroll
      for (int qf = 0; qf < 2; qf++) {
        int q = q0w + qf * 16 + c;
#pragma unroll
        for (int ni = 0; ni < 4; ni++)
#pragma unroll
          for (int jj = 0; jj < 4; jj++) {
            int kvv = kv0 + g * 16 + ni * 4 + jj;
            if (kvv > q) sv[qf][ni][jj] = -3.0e38f;
          }
      }
    }

#pragma unroll
    for (int qf = 0; qf < 2; qf++) {
      // row max: 16 in-lane + cross-g (lanes c, c+16, c+32, c+48)
      float mx = sv[qf][0][0];
#pragma unroll
      for (int ni = 0; ni < 4; ni++)
#pragma unroll
        for (int jj = 0; jj < 4; jj++) mx = fmaxf(mx, sv[qf][ni][jj]);
      mx = fmaxf(mx, __shfl_xor(mx, 16));
      mx = fmaxf(mx, __shfl_xor(mx, 32));
      float mnew = fmaxf(m_run[qf], mx);
      float al = exp2f(m_run[qf] - mnew);
      m_run[qf] = mnew;
      float rs = 0.f;
#pragma unroll
      for (int ni = 0; ni < 4; ni++)
#pragma unroll
        for (int jj = 0; jj < 4; jj++) {
          float p = exp2f(sv[qf][ni][jj] - mnew);
          sv[qf][ni][jj] = p;
          rs += p;
        }
      rs += __shfl_xor(rs, 16);
      rs += __shfl_xor(rs, 32);
      l_run[qf] = l_run[qf] * al + rs;
#pragma unroll
      for (int nh = 0; nh < 4; nh++) acc[qf][nh] *= al;

      // P -> bf16 B-fragments, purely in-lane (kv permutation makes it line up)
      union { unsigned int u[4]; bf16x8 v; } pb0, pb1;
      pb0.u[0] = cvt_pk_bf16(sv[qf][0][0], sv[qf][0][1]);
      pb0.u[1] = cvt_pk_bf16(sv[qf][0][2], sv[qf][0][3]);
      pb0.u[2] = cvt_pk_bf16(sv[qf][1][0], sv[qf][1][1]);
      pb0.u[3] = cvt_pk_bf16(sv[qf][1][2], sv[qf][1][3]);
      pb1.u[0] = cvt_pk_bf16(sv[qf][2][0], sv[qf][2][1]);
      pb1.u[1] = cvt_pk_bf16(sv[qf][2][2], sv[qf][2][3]);
      pb1.u[2] = cvt_pk_bf16(sv[qf][3][0], sv[qf][3][1]);
      pb1.u[3] = cvt_pk_bf16(sv[qf][3][2], sv[qf][3][3]);

      // ctx^T += V^T P^T
#pragma unroll
      for (int nh = 0; nh < 4; nh++) {
        acc[qf][nh] = __builtin_amdgcn_mfma_f32_16x16x32_bf16(va[nh][0], pb0.v, acc[qf][nh], 0, 0, 0);
        acc[qf][nh] = __builtin_amdgcn_mfma_f32_16x16x32_bf16(va[nh][1], pb1.v, acc[qf][nh], 0, 0, 0);
      }
    }
  }

  // epilogue: ctx2d[b*S+q][h*64+hd] = acc/l ; hd = nh*16 + g*4 + jj (uint2 stores)
#pragma unroll
  for (int qf = 0; qf < 2; qf++) {
    float inv = 1.0f / l_run[qf];
    size_t rowoff = ((size_t)b * SS + q0w + qf * 16 + c) * DOUT + h * HD;
#pragma unroll
    for (int nh = 0; nh < 4; nh++) {
      uint2 st;
      st.x = cvt_pk_bf16(acc[qf][nh][0] * inv, acc[qf][nh][1] * inv);
      st.y = cvt_pk_bf16(acc[qf][nh][2] * inv, acc[qf][nh][3] * inv);
      *(uint2*)&ctx[rowoff + nh * 16 + g * 4] = st;
    }
  }
}

// ---------------- launch ----------------

extern "C" void kernel_launch(void* const* d_in, const int* in_sizes, int n_in,
                              void* d_out, int out_size, void* d_ws, size_t ws_size,
                              hipStream_t stream) {
  const float* x  = (const float*)d_in[0];
  const float* Wq = (const float*)d_in[1];
  const float* Wk = (const float*)d_in[2];
  const float* Wv = (const float*)d_in[3];
  const float* Wp = (const float*)d_in[4];
  const float* bp = (const float*)d_in[5];
  float* out = (float*)d_out;

  unsigned short* ws = (unsigned short*)d_ws;
  unsigned short* xb = ws;                      // 8388608 elems (x bf16; later reused as ctx)
  unsigned short* wt = xb + (size_t)MROWS * DIN;       // 4 * 1048576 (Wq^T,Wk^T,Wv^T,Wp^T)
  unsigned short* qs = wt + (size_t)4 * DIN * DOUT;    // 8388608 (Q scaled, [b][h][s][hd])
  unsigned short* kb = qs + (size_t)MROWS * DOUT;      // 8388608 ([b][h][s][hd])
  unsigned short* vt = kb + (size_t)MROWS * DOUT;      // 8388608 ([b][h][hd][s])
  unsigned short* ctx = xb;                            // alias: x dead after projections

  cvt_x_kernel<<<4096, 256, 0, stream>>>(x, xb, (MROWS * DIN) / 4);
  cvt_w_t_kernel<<<dim3(32, 32, 4), dim3(32, 32), 0, stream>>>(Wq, Wk, Wv, Wp, wt);
  gemm_qkv_kernel<<<dim3(8, 64, 3), 256, 0, stream>>>(xb, wt, qs, kb, vt);
  attn_kernel<<<dim3(SS / 128, NH, BB), 256, 0, stream>>>(qs, kb, vt, ctx);
  gemm_out_kernel<<<dim3(8, 64), 256, 0, stream>>>(ctx, wt + (size_t)3 * DIN * DOUT, bp, out);
}

// Round 4
// 213.980 us; speedup vs baseline: 1.6704x; 1.6704x over previous
//
#include <hip/hip_runtime.h>
#include <hip/hip_bf16.h>
#include <stdint.h>

// Problem constants
#define BB   4
#define SS   2048
#define DIN  1024
#define DOUT 1024
#define NH   16
#define HD   64
#define MROWS (BB * SS)   // 8192

typedef __bf16 bf16x8 __attribute__((ext_vector_type(8)));
typedef float  f32x4  __attribute__((ext_vector_type(4)));

__device__ __forceinline__ unsigned short f2bf(float f) {
  union { float f; uint32_t u; } v; v.f = f;
  uint32_t u = v.u;
  uint32_t r = (u + 0x7fffu + ((u >> 16) & 1u)) >> 16;
  return (unsigned short)r;
}

// v_cvt_pk_bf16_f32: lo -> low16, hi -> high16 (RNE)
__device__ __forceinline__ unsigned int cvt_pk_bf16(float lo, float hi) {
  unsigned int r;
  asm("v_cvt_pk_bf16_f32 %0, %1, %2" : "=v"(r) : "v"(lo), "v"(hi));
  return r;
}

#define GLOAD_LDS16(gsrc, ldst)                                                   \
  __builtin_amdgcn_global_load_lds(                                               \
      (const __attribute__((address_space(1))) void*)(gsrc),                      \
      (__attribute__((address_space(3))) void*)(ldst), 16, 0, 0)

// ---------------- conversion kernels ----------------

__global__ void cvt_x_kernel(const float* __restrict__ in,
                             unsigned short* __restrict__ out, int n4) {
  int i = blockIdx.x * blockDim.x + threadIdx.x;
  int stride = gridDim.x * blockDim.x;
  for (; i < n4; i += stride) {
    float4 f = ((const float4*)in)[i];
    ushort4 o;
    o.x = f2bf(f.x); o.y = f2bf(f.y); o.z = f2bf(f.z); o.w = f2bf(f.w);
    ((ushort4*)out)[i] = o;
  }
}

// transpose-convert: out[n][k] = bf16(W[k][n]), per blockIdx.z matrix
__global__ void cvt_w_t_kernel(const float* __restrict__ w0,
                               const float* __restrict__ w1,
                               const float* __restrict__ w2,
                               const float* __restrict__ w3,
                               unsigned short* __restrict__ out) {
  __shared__ float tile[32][33];
  const float* src = (blockIdx.z == 0) ? w0 : (blockIdx.z == 1) ? w1
                   : (blockIdx.z == 2) ? w2 : w3;
  unsigned short* dst = out + (size_t)blockIdx.z * (DIN * DOUT);
  int kb = blockIdx.x * 32, nb = blockIdx.y * 32;
  tile[threadIdx.y][threadIdx.x] = src[(size_t)(kb + threadIdx.y) * DOUT + nb + threadIdx.x];
  __syncthreads();
  dst[(size_t)(nb + threadIdx.y) * DIN + kb + threadIdx.x] = f2bf(tile[threadIdx.x][threadIdx.y]);
}

// ---------------- GEMM core: 128x128 tile, 4 waves, global_load_lds (m97) ----
__device__ __forceinline__ void gemm_core(const unsigned short* __restrict__ A,
                                          const unsigned short* __restrict__ BT,
                                          f32x4 (&acc)[4][4]) {
  const int tid  = threadIdx.x;
  const int lane = tid & 63;
  const int wave = tid >> 6;
  const int wm = (wave >> 1) * 64, wn = (wave & 1) * 64;
  const int g = lane >> 4, c = lane & 15;

  __shared__ __align__(16) unsigned short As[128 * 32];
  __shared__ __align__(16) unsigned short Bs[128 * 32];

#pragma unroll
  for (int mi = 0; mi < 4; mi++)
#pragma unroll
    for (int ni = 0; ni < 4; ni++)
      acc[mi][ni] = (f32x4){0.f, 0.f, 0.f, 0.f};

  const int rj0 = (0 * 4 + wave) * 16 + (lane >> 2);
  const int rj1 = (1 * 4 + wave) * 16 + (lane >> 2);
  const int gcol = (lane & 3) * 8;
  const unsigned short* Ag0 = A + (size_t)rj0 * 1024 + gcol;
  const unsigned short* Ag1 = A + (size_t)rj1 * 1024 + gcol;
  const unsigned short* Bg0 = BT + (size_t)rj0 * 1024 + gcol;
  const unsigned short* Bg1 = BT + (size_t)rj1 * 1024 + gcol;
  unsigned short* As0 = &As[(0 * 4 + wave) * 512 + lane * 8];
  unsigned short* As1 = &As[(1 * 4 + wave) * 512 + lane * 8];
  unsigned short* Bs0 = &Bs[(0 * 4 + wave) * 512 + lane * 8];
  unsigned short* Bs1 = &Bs[(1 * 4 + wave) * 512 + lane * 8];

  for (int k0 = 0; k0 < 1024; k0 += 32) {
    __syncthreads();
    GLOAD_LDS16(Ag0 + k0, As0);
    GLOAD_LDS16(Ag1 + k0, As1);
    GLOAD_LDS16(Bg0 + k0, Bs0);
    GLOAD_LDS16(Bg1 + k0, Bs1);
    __syncthreads();
    bf16x8 a[4], b[4];
#pragma unroll
    for (int mi = 0; mi < 4; mi++)
      a[mi] = *(const bf16x8*)&As[(wm + mi * 16 + c) * 32 + g * 8];
#pragma unroll
    for (int ni = 0; ni < 4; ni++)
      b[ni] = *(const bf16x8*)&Bs[(wn + ni * 16 + c) * 32 + g * 8];
#pragma unroll
    for (int mi = 0; mi < 4; mi++)
#pragma unroll
      for (int ni = 0; ni < 4; ni++)
        acc[mi][ni] = __builtin_amdgcn_mfma_f32_16x16x32_bf16(a[mi], b[ni], acc[mi][ni], 0, 0, 0);
  }
}

// QKV projection. z=0: Q (scaled log2e/8) -> [b][h][s][hd]; z=1: K; z=2: V^T [b][h][hd][s]
__global__ __launch_bounds__(256) void gemm_qkv_kernel(
    const unsigned short* __restrict__ xb, const unsigned short* __restrict__ wt,
    unsigned short* __restrict__ qs, unsigned short* __restrict__ kbuf,
    unsigned short* __restrict__ vt) {
  const int nT = blockIdx.x, mT = blockIdx.y, z = blockIdx.z;
  f32x4 acc[4][4];
  gemm_core(xb + (size_t)mT * 128 * 1024,
            wt + (size_t)z * (DIN * DOUT) + (size_t)nT * 128 * 1024, acc);

  const int tid = threadIdx.x, lane = tid & 63, wave = tid >> 6;
  const int wm = (wave >> 1) * 64, wn = (wave & 1) * 64;
  const int g = lane >> 4, c = lane & 15;
  // Q folded scale: (1/sqrt(HD)) * log2(e) so attention uses exp2
  const float scale = (z == 0) ? 0.18033688011112042f : 1.0f;
  unsigned short* dstQK = (z == 0) ? qs : kbuf;
#pragma unroll
  for (int mi = 0; mi < 4; mi++)
#pragma unroll
    for (int ni = 0; ni < 4; ni++) {
      int n = nT * 128 + wn + ni * 16 + c;
      int h = n >> 6, hd = n & 63;
#pragma unroll
      for (int jj = 0; jj < 4; jj++) {
        int m = mT * 128 + wm + mi * 16 + g * 4 + jj;
        int b = m >> 11, s = m & 2047;
        unsigned short val = f2bf(acc[mi][ni][jj] * scale);
        if (z < 2)
          dstQK[(((size_t)(b * NH + h)) * SS + s) * HD + hd] = val;
        else
          vt[(((size_t)(b * NH + h)) * HD + hd) * SS + s] = val;
      }
    }
}

// Output projection: out = ctx @ Wp + bp (fp32 out)
__global__ __launch_bounds__(256) void gemm_out_kernel(
    const unsigned short* __restrict__ ctx, const unsigned short* __restrict__ wtp,
    const float* __restrict__ bp, float* __restrict__ out) {
  const int nT = blockIdx.x, mT = blockIdx.y;
  f32x4 acc[4][4];
  gemm_core(ctx + (size_t)mT * 128 * 1024, wtp + (size_t)nT * 128 * 1024, acc);

  const int tid = threadIdx.x, lane = tid & 63, wave = tid >> 6;
  const int wm = (wave >> 1) * 64, wn = (wave & 1) * 64;
  const int g = lane >> 4, c = lane & 15;
#pragma unroll
  for (int mi = 0; mi < 4; mi++)
#pragma unroll
    for (int ni = 0; ni < 4; ni++) {
      int n = nT * 128 + wn + ni * 16 + c;
      float bias = bp[n];
#pragma unroll
      for (int jj = 0; jj < 4; jj++) {
        int m = mT * 128 + wm + mi * 16 + g * 4 + jj;
        out[(size_t)m * DOUT + n] = acc[mi][ni][jj] + bias;
      }
    }
}

// ---------------- flash attention: 8-wave LDS-shared, balanced pairing -------
// grid: (4, H, B); block = 512 threads = 8 waves; each block processes q-block
// (7-pairIdx) then (pairIdx) [256 q rows each] -> uniform 36 tiles/block.
// K/V tiles (64 kv x 64 hd) double-buffered in LDS, shared by all 8 waves.
// Async-stage: global->reg loads for t+1 issued before compute of t; ds_write
// + one barrier after. In-register softmax (swapped QK^T, kv-permuted frags).
__global__ __launch_bounds__(512) void attn_kernel(
    const unsigned short* __restrict__ qs, const unsigned short* __restrict__ kbuf,
    const unsigned short* __restrict__ vt, unsigned short* __restrict__ ctx) {
  const int pairIdx = blockIdx.x, h = blockIdx.y, b = blockIdx.z;
  const int tid = threadIdx.x, lane = tid & 63, w = tid >> 6;
  const int g = lane >> 4, c = lane & 15;
  const size_t bh = (size_t)(b * NH + h);
  const unsigned short* Q = qs + bh * SS * HD;
  const unsigned short* K = kbuf + bh * SS * HD;
  const unsigned short* V = vt + bh * HD * SS;   // [hd][s]

  // double-buffered K/V tiles: 64 rows x 64 elems (128 B), 32 KB total
  __shared__ __align__(16) unsigned short Klds[2][64 * 64];
  __shared__ __align__(16) unsigned short Vlds[2][64 * 64];

  // staging: thread -> (row = tid>>3, chunk = tid&7); 1 K-chunk + 1 V-chunk
  const int srow = tid >> 3, scol = tid & 7;
  const int sK_w = ((srow & 3) << 1) | ((srow >> 4) & 1);   // K swizzle
  const int sV_w = ((srow & 3) << 1) | ((srow >> 2) & 1);   // V swizzle
  const int kdst = srow * 64 + ((scol ^ sK_w) * 8);
  const int vdst = srow * 64 + ((scol ^ sV_w) * 8);
  const unsigned short* Kg0 = K + (size_t)srow * HD + scol * 8;   // + t*4096
  const unsigned short* Vg0 = V + (size_t)srow * SS + scol * 8;   // + t*64

  // per-lane LDS read offsets (elems), loop-invariant
  // ka[ni][kk]: r = (c>>2)*16 + ni*4 + (c&3); cc = kk*4+g; s_K(r)
  // va[nh][k2]: r = nh*16 + c;                cc = 2g+k2;  s_V(r)
  int kaoff[4][2], vaoff[4][2];
#pragma unroll
  for (int ni = 0; ni < 4; ni++) {
    int r = (c >> 2) * 16 + ni * 4 + (c & 3);
    int s = ((r & 3) << 1) | ((r >> 4) & 1);
#pragma unroll
    for (int kk = 0; kk < 2; kk++)
      kaoff[ni][kk] = r * 64 + (((kk * 4 + g) ^ s) * 8);
  }
#pragma unroll
  for (int nh = 0; nh < 4; nh++) {
    int r = nh * 16 + c;
    int s = ((r & 3) << 1) | ((r >> 2) & 1);
#pragma unroll
    for (int k2 = 0; k2 < 2; k2++)
      vaoff[nh][k2] = r * 64 + (((2 * g + k2) ^ s) * 8);
  }

#pragma unroll 1
  for (int seg = 0; seg < 2; ++seg) {
    const int qtB = (seg == 0) ? (3 - pairIdx + 4) : pairIdx;   // 7-p then p
    const int q0 = qtB * 256 + w * 32;
    const int nt = 4 * qtB + 4;        // block-level tile count
    const int ntw = q0 / 64 + 1;       // this wave's tile count

    bf16x8 aq[2][2];
#pragma unroll
    for (int qf = 0; qf < 2; qf++)
#pragma unroll
      for (int kk = 0; kk < 2; kk++)
        aq[qf][kk] = *(const bf16x8*)&Q[(size_t)(q0 + qf * 16 + c) * HD + kk * 32 + g * 8];

    float m_run[2] = {-3.0e38f, -3.0e38f};
    float l_run[2] = {0.f, 0.f};
    f32x4 acc[2][4];
#pragma unroll
    for (int qf = 0; qf < 2; qf++)
#pragma unroll
      for (int nh = 0; nh < 4; nh++) acc[qf][nh] = (f32x4){0.f, 0.f, 0.f, 0.f};

    // prologue: stage tile 0
    {
      uint4 k0 = *(const uint4*)Kg0;
      uint4 v0 = *(const uint4*)Vg0;
      __syncthreads();   // previous segment's readers done
      *(uint4*)&Klds[0][kdst] = k0;
      *(uint4*)&Vlds[0][vdst] = v0;
      __syncthreads();
    }
    int cur = 0;

#pragma unroll 1
    for (int t = 0; t < nt; ++t) {
      const bool more = (t + 1 < nt);
      uint4 knx, vnx;
      if (more) {   // issue-early: latency hides under this tile's compute
        knx = *(const uint4*)(Kg0 + (size_t)(t + 1) * 64 * HD);
        vnx = *(const uint4*)(Vg0 + (size_t)(t + 1) * 64);
      }
      if (t < ntw) {
        const unsigned short* Kl = Klds[cur];
        const unsigned short* Vl = Vlds[cur];
        bf16x8 ka[4][2], va[4][2];
#pragma unroll
        for (int ni = 0; ni < 4; ni++)
#pragma unroll
          for (int kk = 0; kk < 2; kk++)
            ka[ni][kk] = *(const bf16x8*)&Kl[kaoff[ni][kk]];
#pragma unroll
        for (int nh = 0; nh < 4; nh++)
#pragma unroll
          for (int k2 = 0; k2 < 2; k2++)
            va[nh][k2] = *(const bf16x8*)&Vl[vaoff[nh][k2]];

        // S^T = K Q^T: reg jj of frag ni -> kv = t*64 + 16g + 4ni + jj, q = q0+qf*16+c
        f32x4 sv[2][4];
        __builtin_amdgcn_s_setprio(1);
#pragma unroll
        for (int qf = 0; qf < 2; qf++)
#pragma unroll
          for (int ni = 0; ni < 4; ni++) {
            f32x4 z = (f32x4){0.f, 0.f, 0.f, 0.f};
            z = __builtin_amdgcn_mfma_f32_16x16x32_bf16(ka[ni][0], aq[qf][0], z, 0, 0, 0);
            sv[qf][ni] = __builtin_amdgcn_mfma_f32_16x16x32_bf16(ka[ni][1], aq[qf][1], z, 0, 0, 0);
          }
        __builtin_amdgcn_s_setprio(0);

        if (t == ntw - 1) {   // diagonal tile: causal mask
#pragma unroll
          for (int qf = 0; qf < 2; qf++) {
            int q = q0 + qf * 16 + c;
#pragma unroll
            for (int ni = 0; ni < 4; ni++)
#pragma unroll
              for (int jj = 0; jj < 4; jj++) {
                int kvv = t * 64 + g * 16 + ni * 4 + jj;
                if (kvv > q) sv[qf][ni][jj] = -3.0e38f;
              }
          }
        }

#pragma unroll
        for (int qf = 0; qf < 2; qf++) {
          float mx = sv[qf][0][0];
#pragma unroll
          for (int ni = 0; ni < 4; ni++)
#pragma unroll
            for (int jj = 0; jj < 4; jj++) mx = fmaxf(mx, sv[qf][ni][jj]);
          mx = fmaxf(mx, __shfl_xor(mx, 16));
          mx = fmaxf(mx, __shfl_xor(mx, 32));
          float mnew = fmaxf(m_run[qf], mx);
          float al = exp2f(m_run[qf] - mnew);
          m_run[qf] = mnew;
          float rs = 0.f;
#pragma unroll
          for (int ni = 0; ni < 4; ni++)
#pragma unroll
            for (int jj = 0; jj < 4; jj++) {
              float p = exp2f(sv[qf][ni][jj] - mnew);
              sv[qf][ni][jj] = p;
              rs += p;
            }
          rs += __shfl_xor(rs, 16);
          rs += __shfl_xor(rs, 32);
          l_run[qf] = l_run[qf] * al + rs;
#pragma unroll
          for (int nh = 0; nh < 4; nh++) acc[qf][nh] *= al;

          // P -> bf16 B-fragments, purely in-lane
          union { unsigned int u[4]; bf16x8 v; } pb0, pb1;
          pb0.u[0] = cvt_pk_bf16(sv[qf][0][0], sv[qf][0][1]);
          pb0.u[1] = cvt_pk_bf16(sv[qf][0][2], sv[qf][0][3]);
          pb0.u[2] = cvt_pk_bf16(sv[qf][1][0], sv[qf][1][1]);
          pb0.u[3] = cvt_pk_bf16(sv[qf][1][2], sv[qf][1][3]);
          pb1.u[0] = cvt_pk_bf16(sv[qf][2][0], sv[qf][2][1]);
          pb1.u[1] = cvt_pk_bf16(sv[qf][2][2], sv[qf][2][3]);
          pb1.u[2] = cvt_pk_bf16(sv[qf][3][0], sv[qf][3][1]);
          pb1.u[3] = cvt_pk_bf16(sv[qf][3][2], sv[qf][3][3]);

          __builtin_amdgcn_s_setprio(1);
#pragma unroll
          for (int nh = 0; nh < 4; nh++) {
            acc[qf][nh] = __builtin_amdgcn_mfma_f32_16x16x32_bf16(va[nh][0], pb0.v, acc[qf][nh], 0, 0, 0);
            acc[qf][nh] = __builtin_amdgcn_mfma_f32_16x16x32_bf16(va[nh][1], pb1.v, acc[qf][nh], 0, 0, 0);
          }
          __builtin_amdgcn_s_setprio(0);
        }
      }
      if (more) {   // write-late: next tile into the other buffer
        *(uint4*)&Klds[cur ^ 1][kdst] = knx;
        *(uint4*)&Vlds[cur ^ 1][vdst] = vnx;
        __syncthreads();
        cur ^= 1;
      }
    }

    // epilogue: ctx2d[b*S+q][h*64+hd] = acc/l ; hd = nh*16 + g*4 + jj
#pragma unroll
    for (int qf = 0; qf < 2; qf++) {
      float inv = 1.0f / l_run[qf];
      size_t rowoff = ((size_t)b * SS + q0 + qf * 16 + c) * DOUT + h * HD;
#pragma unroll
      for (int nh = 0; nh < 4; nh++) {
        uint2 st;
        st.x = cvt_pk_bf16(acc[qf][nh][0] * inv, acc[qf][nh][1] * inv);
        st.y = cvt_pk_bf16(acc[qf][nh][2] * inv, acc[qf][nh][3] * inv);
        *(uint2*)&ctx[rowoff + nh * 16 + g * 4] = st;
      }
    }
  }
}

// ---------------- launch ----------------

extern "C" void kernel_launch(void* const* d_in, const int* in_sizes, int n_in,
                              void* d_out, int out_size, void* d_ws, size_t ws_size,
                              hipStream_t stream) {
  const float* x  = (const float*)d_in[0];
  const float* Wq = (const float*)d_in[1];
  const float* Wk = (const float*)d_in[2];
  const float* Wv = (const float*)d_in[3];
  const float* Wp = (const float*)d_in[4];
  const float* bp = (const float*)d_in[5];
  float* out = (float*)d_out;

  unsigned short* ws = (unsigned short*)d_ws;
  unsigned short* xb = ws;                      // 8388608 elems (x bf16; later reused as ctx)
  unsigned short* wt = xb + (size_t)MROWS * DIN;       // 4 * 1048576 (Wq^T,Wk^T,Wv^T,Wp^T)
  unsigned short* qs = wt + (size_t)4 * DIN * DOUT;    // 8388608 (Q scaled, [b][h][s][hd])
  unsigned short* kb = qs + (size_t)MROWS * DOUT;      // 8388608 ([b][h][s][hd])
  unsigned short* vt = kb + (size_t)MROWS * DOUT;      // 8388608 ([b][h][hd][s])
  unsigned short* ctx = xb;                            // alias: x dead after projections

  cvt_x_kernel<<<4096, 256, 0, stream>>>(x, xb, (MROWS * DIN) / 4);
  cvt_w_t_kernel<<<dim3(32, 32, 4), dim3(32, 32), 0, stream>>>(Wq, Wk, Wv, Wp, wt);
  gemm_qkv_kernel<<<dim3(8, 64, 3), 256, 0, stream>>>(xb, wt, qs, kb, vt);
  attn_kernel<<<dim3(4, NH, BB), 512, 0, stream>>>(qs, kb, vt, ctx);
  gemm_out_kernel<<<dim3(8, 64), 256, 0, stream>>>(ctx, wt + (size_t)3 * DIN * DOUT, bp, out);
}

// Round 5
// 213.632 us; speedup vs baseline: 1.6732x; 1.0016x over previous
//
#include <hip/hip_runtime.h>
#include <hip/hip_bf16.h>
#include <stdint.h>

// Problem constants
#define BB   4
#define SS   2048
#define DIN  1024
#define DOUT 1024
#define NH   16
#define HD   64
#define MROWS (BB * SS)   // 8192

typedef __bf16 bf16x8 __attribute__((ext_vector_type(8)));
typedef float  f32x4  __attribute__((ext_vector_type(4)));

__device__ __forceinline__ unsigned short f2bf(float f) {
  union { float f; uint32_t u; } v; v.f = f;
  uint32_t u = v.u;
  uint32_t r = (u + 0x7fffu + ((u >> 16) & 1u)) >> 16;
  return (unsigned short)r;
}

// v_cvt_pk_bf16_f32: lo -> low16, hi -> high16 (RNE)
__device__ __forceinline__ unsigned int cvt_pk_bf16(float lo, float hi) {
  unsigned int r;
  asm("v_cvt_pk_bf16_f32 %0, %1, %2" : "=v"(r) : "v"(lo), "v"(hi));
  return r;
}

#define GLOAD_LDS16(gsrc, ldst)                                                   \
  __builtin_amdgcn_global_load_lds(                                               \
      (const __attribute__((address_space(1))) void*)(gsrc),                      \
      (__attribute__((address_space(3))) void*)(ldst), 16, 0, 0)

// ---------------- conversion kernels ----------------

__global__ void cvt_x_kernel(const float* __restrict__ in,
                             unsigned short* __restrict__ out, int n4) {
  int i = blockIdx.x * blockDim.x + threadIdx.x;
  int stride = gridDim.x * blockDim.x;
  for (; i < n4; i += stride) {
    float4 f = ((const float4*)in)[i];
    ushort4 o;
    o.x = f2bf(f.x); o.y = f2bf(f.y); o.z = f2bf(f.z); o.w = f2bf(f.w);
    ((ushort4*)out)[i] = o;
  }
}

// transpose-convert: out[n][k] = bf16(W[k][n]), per blockIdx.z matrix
__global__ void cvt_w_t_kernel(const float* __restrict__ w0,
                               const float* __restrict__ w1,
                               const float* __restrict__ w2,
                               const float* __restrict__ w3,
                               unsigned short* __restrict__ out) {
  __shared__ float tile[32][33];
  const float* src = (blockIdx.z == 0) ? w0 : (blockIdx.z == 1) ? w1
                   : (blockIdx.z == 2) ? w2 : w3;
  unsigned short* dst = out + (size_t)blockIdx.z * (DIN * DOUT);
  int kb = blockIdx.x * 32, nb = blockIdx.y * 32;
  tile[threadIdx.y][threadIdx.x] = src[(size_t)(kb + threadIdx.y) * DOUT + nb + threadIdx.x];
  __syncthreads();
  dst[(size_t)(nb + threadIdx.y) * DIN + kb + threadIdx.x] = f2bf(tile[threadIdx.x][threadIdx.y]);
}

// ---------------- GEMM core: 128x128 tile, 4 waves, 2-phase pipeline ---------
// Double-buffered LDS; STAGE(t+1) issued before compute(t); ONE barrier/iter.
// Bank-conflict-free via source-pre-swizzle (LDS dest linear, rule 21):
//   LDS slot (row r, chunk q) holds global chunk q ^ ((r>>1)&3).
__device__ __forceinline__ void gemm_core(const unsigned short* __restrict__ A,
                                          const unsigned short* __restrict__ BT,
                                          f32x4 (&acc)[4][4]) {
  const int tid  = threadIdx.x;
  const int lane = tid & 63;
  const int wave = tid >> 6;
  const int wm = (wave >> 1) * 64, wn = (wave & 1) * 64;
  const int g = lane >> 4, c = lane & 15;

  __shared__ __align__(16) unsigned short As[2][128 * 32];
  __shared__ __align__(16) unsigned short Bs[2][128 * 32];

#pragma unroll
  for (int mi = 0; mi < 4; mi++)
#pragma unroll
    for (int ni = 0; ni < 4; ni++)
      acc[mi][ni] = (f32x4){0.f, 0.f, 0.f, 0.f};

  // staging: call j covers rows [(j*4+wave)*16, +16); lane -> row (lane>>2),
  // LDS chunk (lane&3); global chunk pre-swizzled by sl = (lane>>3)&3
  const int sl = (lane >> 3) & 3;
  const int gcol = ((lane & 3) ^ sl) * 8;
  const int rj0 = (0 * 4 + wave) * 16 + (lane >> 2);
  const int rj1 = (1 * 4 + wave) * 16 + (lane >> 2);
  const unsigned short* Ag0 = A + (size_t)rj0 * 1024 + gcol;
  const unsigned short* Ag1 = A + (size_t)rj1 * 1024 + gcol;
  const unsigned short* Bg0 = BT + (size_t)rj0 * 1024 + gcol;
  const unsigned short* Bg1 = BT + (size_t)rj1 * 1024 + gcol;
  const int d0 = (0 * 4 + wave) * 512 + lane * 8;   // linear LDS dest (elems)
  const int d1 = (1 * 4 + wave) * 512 + lane * 8;

  // fragment-read swizzle: row r = wm|wn + mi*16 + c -> xor = (c>>1)&3
  const int rx = (c >> 1) & 3;
  int aoff[4], boff[4];
#pragma unroll
  for (int mi = 0; mi < 4; mi++) aoff[mi] = (wm + mi * 16 + c) * 32 + ((g ^ rx) * 8);
#pragma unroll
  for (int ni = 0; ni < 4; ni++) boff[ni] = (wn + ni * 16 + c) * 32 + ((g ^ rx) * 8);

  // prologue: stage tile 0 into buffer 0
  GLOAD_LDS16(Ag0, &As[0][d0]);
  GLOAD_LDS16(Ag1, &As[0][d1]);
  GLOAD_LDS16(Bg0, &Bs[0][d0]);
  GLOAD_LDS16(Bg1, &Bs[0][d1]);
  __syncthreads();   // drains vmcnt(0): tile 0 resident

  int cur = 0;
#pragma unroll 1
  for (int kt = 0; kt < 32; ++kt) {
    if (kt + 1 < 32) {   // issue next tile's loads; latency hides under MFMA
      const int k0 = (kt + 1) * 32;
      GLOAD_LDS16(Ag0 + k0, &As[cur ^ 1][d0]);
      GLOAD_LDS16(Ag1 + k0, &As[cur ^ 1][d1]);
      GLOAD_LDS16(Bg0 + k0, &Bs[cur ^ 1][d0]);
      GLOAD_LDS16(Bg1 + k0, &Bs[cur ^ 1][d1]);
    }
    bf16x8 a[4], b[4];
#pragma unroll
    for (int mi = 0; mi < 4; mi++) a[mi] = *(const bf16x8*)&As[cur][aoff[mi]];
#pragma unroll
    for (int ni = 0; ni < 4; ni++) b[ni] = *(const bf16x8*)&Bs[cur][boff[ni]];
    __builtin_amdgcn_s_setprio(1);
#pragma unroll
    for (int mi = 0; mi < 4; mi++)
#pragma unroll
      for (int ni = 0; ni < 4; ni++)
        acc[mi][ni] = __builtin_amdgcn_mfma_f32_16x16x32_bf16(a[mi], b[ni], acc[mi][ni], 0, 0, 0);
    __builtin_amdgcn_s_setprio(0);
    __syncthreads();   // drains vmcnt(0): next tile resident; readers done
    cur ^= 1;
  }
}

// QKV projection. z=0: Q (scaled log2e/8) -> [b][h][s][hd]; z=1: K; z=2: V^T [b][h][hd][s]
__global__ __launch_bounds__(256) void gemm_qkv_kernel(
    const unsigned short* __restrict__ xb, const unsigned short* __restrict__ wt,
    unsigned short* __restrict__ qs, unsigned short* __restrict__ kbuf,
    unsigned short* __restrict__ vt) {
  const int nT = blockIdx.x, mT = blockIdx.y, z = blockIdx.z;
  f32x4 acc[4][4];
  gemm_core(xb + (size_t)mT * 128 * 1024,
            wt + (size_t)z * (DIN * DOUT) + (size_t)nT * 128 * 1024, acc);

  const int tid = threadIdx.x, lane = tid & 63, wave = tid >> 6;
  const int wm = (wave >> 1) * 64, wn = (wave & 1) * 64;
  const int g = lane >> 4, c = lane & 15;
  // Q folded scale: (1/sqrt(HD)) * log2(e) so attention uses exp2
  const float scale = (z == 0) ? 0.18033688011112042f : 1.0f;
  unsigned short* dstQK = (z == 0) ? qs : kbuf;
#pragma unroll
  for (int mi = 0; mi < 4; mi++)
#pragma unroll
    for (int ni = 0; ni < 4; ni++) {
      int n = nT * 128 + wn + ni * 16 + c;
      int h = n >> 6, hd = n & 63;
#pragma unroll
      for (int jj = 0; jj < 4; jj++) {
        int m = mT * 128 + wm + mi * 16 + g * 4 + jj;
        int b = m >> 11, s = m & 2047;
        unsigned short val = f2bf(acc[mi][ni][jj] * scale);
        if (z < 2)
          dstQK[(((size_t)(b * NH + h)) * SS + s) * HD + hd] = val;
        else
          vt[(((size_t)(b * NH + h)) * HD + hd) * SS + s] = val;
      }
    }
}

// Output projection: out = ctx @ Wp + bp (fp32 out)
__global__ __launch_bounds__(256) void gemm_out_kernel(
    const unsigned short* __restrict__ ctx, const unsigned short* __restrict__ wtp,
    const float* __restrict__ bp, float* __restrict__ out) {
  const int nT = blockIdx.x, mT = blockIdx.y;
  f32x4 acc[4][4];
  gemm_core(ctx + (size_t)mT * 128 * 1024, wtp + (size_t)nT * 128 * 1024, acc);

  const int tid = threadIdx.x, lane = tid & 63, wave = tid >> 6;
  const int wm = (wave >> 1) * 64, wn = (wave & 1) * 64;
  const int g = lane >> 4, c = lane & 15;
#pragma unroll
  for (int mi = 0; mi < 4; mi++)
#pragma unroll
    for (int ni = 0; ni < 4; ni++) {
      int n = nT * 128 + wn + ni * 16 + c;
      float bias = bp[n];
#pragma unroll
      for (int jj = 0; jj < 4; jj++) {
        int m = mT * 128 + wm + mi * 16 + g * 4 + jj;
        out[(size_t)m * DOUT + n] = acc[mi][ni][jj] + bias;
      }
    }
}

// ---------------- flash attention: 8-wave LDS-shared, balanced pairing -------
// grid: (4, H, B); block = 512 threads = 8 waves; each block processes q-block
// (7-pairIdx) then (pairIdx) [256 q rows each] -> uniform 36 tiles/block.
// K/V tiles (64 kv x 64 hd) double-buffered in LDS, shared by all 8 waves.
// Async-stage: global->reg loads for t+1 issued before compute of t; ds_write
// + one barrier after. In-register softmax (swapped QK^T, kv-permuted frags).
__global__ __launch_bounds__(512) void attn_kernel(
    const unsigned short* __restrict__ qs, const unsigned short* __restrict__ kbuf,
    const unsigned short* __restrict__ vt, unsigned short* __restrict__ ctx) {
  const int pairIdx = blockIdx.x, h = blockIdx.y, b = blockIdx.z;
  const int tid = threadIdx.x, lane = tid & 63, w = tid >> 6;
  const int g = lane >> 4, c = lane & 15;
  const size_t bh = (size_t)(b * NH + h);
  const unsigned short* Q = qs + bh * SS * HD;
  const unsigned short* K = kbuf + bh * SS * HD;
  const unsigned short* V = vt + bh * HD * SS;   // [hd][s]

  // double-buffered K/V tiles: 64 rows x 64 elems (128 B), 32 KB total
  __shared__ __align__(16) unsigned short Klds[2][64 * 64];
  __shared__ __align__(16) unsigned short Vlds[2][64 * 64];

  // staging: thread -> (row = tid>>3, chunk = tid&7); 1 K-chunk + 1 V-chunk
  const int srow = tid >> 3, scol = tid & 7;
  const int sK_w = ((srow & 3) << 1) | ((srow >> 4) & 1);   // K swizzle
  const int sV_w = ((srow & 3) << 1) | ((srow >> 2) & 1);   // V swizzle
  const int kdst = srow * 64 + ((scol ^ sK_w) * 8);
  const int vdst = srow * 64 + ((scol ^ sV_w) * 8);
  const unsigned short* Kg0 = K + (size_t)srow * HD + scol * 8;   // + t*4096
  const unsigned short* Vg0 = V + (size_t)srow * SS + scol * 8;   // + t*64

  // per-lane LDS read offsets (elems), loop-invariant
  // ka[ni][kk]: r = (c>>2)*16 + ni*4 + (c&3); cc = kk*4+g; s_K(r)
  // va[nh][k2]: r = nh*16 + c;                cc = 2g+k2;  s_V(r)
  int kaoff[4][2], vaoff[4][2];
#pragma unroll
  for (int ni = 0; ni < 4; ni++) {
    int r = (c >> 2) * 16 + ni * 4 + (c & 3);
    int s = ((r & 3) << 1) | ((r >> 4) & 1);
#pragma unroll
    for (int kk = 0; kk < 2; kk++)
      kaoff[ni][kk] = r * 64 + (((kk * 4 + g) ^ s) * 8);
  }
#pragma unroll
  for (int nh = 0; nh < 4; nh++) {
    int r = nh * 16 + c;
    int s = ((r & 3) << 1) | ((r >> 2) & 1);
#pragma unroll
    for (int k2 = 0; k2 < 2; k2++)
      vaoff[nh][k2] = r * 64 + (((2 * g + k2) ^ s) * 8);
  }

#pragma unroll 1
  for (int seg = 0; seg < 2; ++seg) {
    const int qtB = (seg == 0) ? (3 - pairIdx + 4) : pairIdx;   // 7-p then p
    const int q0 = qtB * 256 + w * 32;
    const int nt = 4 * qtB + 4;        // block-level tile count
    const int ntw = q0 / 64 + 1;       // this wave's tile count

    bf16x8 aq[2][2];
#pragma unroll
    for (int qf = 0; qf < 2; qf++)
#pragma unroll
      for (int kk = 0; kk < 2; kk++)
        aq[qf][kk] = *(const bf16x8*)&Q[(size_t)(q0 + qf * 16 + c) * HD + kk * 32 + g * 8];

    float m_run[2] = {-3.0e38f, -3.0e38f};
    float l_run[2] = {0.f, 0.f};
    f32x4 acc[2][4];
#pragma unroll
    for (int qf = 0; qf < 2; qf++)
#pragma unroll
      for (int nh = 0; nh < 4; nh++) acc[qf][nh] = (f32x4){0.f, 0.f, 0.f, 0.f};

    // prologue: stage tile 0
    {
      uint4 k0 = *(const uint4*)Kg0;
      uint4 v0 = *(const uint4*)Vg0;
      __syncthreads();   // previous segment's readers done
      *(uint4*)&Klds[0][kdst] = k0;
      *(uint4*)&Vlds[0][vdst] = v0;
      __syncthreads();
    }
    int cur = 0;

#pragma unroll 1
    for (int t = 0; t < nt; ++t) {
      const bool more = (t + 1 < nt);
      uint4 knx, vnx;
      if (more) {   // issue-early: latency hides under this tile's compute
        knx = *(const uint4*)(Kg0 + (size_t)(t + 1) * 64 * HD);
        vnx = *(const uint4*)(Vg0 + (size_t)(t + 1) * 64);
      }
      if (t < ntw) {
        const unsigned short* Kl = Klds[cur];
        const unsigned short* Vl = Vlds[cur];
        bf16x8 ka[4][2], va[4][2];
#pragma unroll
        for (int ni = 0; ni < 4; ni++)
#pragma unroll
          for (int kk = 0; kk < 2; kk++)
            ka[ni][kk] = *(const bf16x8*)&Kl[kaoff[ni][kk]];
#pragma unroll
        for (int nh = 0; nh < 4; nh++)
#pragma unroll
          for (int k2 = 0; k2 < 2; k2++)
            va[nh][k2] = *(const bf16x8*)&Vl[vaoff[nh][k2]];

        // S^T = K Q^T: reg jj of frag ni -> kv = t*64 + 16g + 4ni + jj, q = q0+qf*16+c
        f32x4 sv[2][4];
        __builtin_amdgcn_s_setprio(1);
#pragma unroll
        for (int qf = 0; qf < 2; qf++)
#pragma unroll
          for (int ni = 0; ni < 4; ni++) {
            f32x4 z = (f32x4){0.f, 0.f, 0.f, 0.f};
            z = __builtin_amdgcn_mfma_f32_16x16x32_bf16(ka[ni][0], aq[qf][0], z, 0, 0, 0);
            sv[qf][ni] = __builtin_amdgcn_mfma_f32_16x16x32_bf16(ka[ni][1], aq[qf][1], z, 0, 0, 0);
          }
        __builtin_amdgcn_s_setprio(0);

        if (t == ntw - 1) {   // diagonal tile: causal mask
#pragma unroll
          for (int qf = 0; qf < 2; qf++) {
            int q = q0 + qf * 16 + c;
#pragma unroll
            for (int ni = 0; ni < 4; ni++)
#pragma unroll
              for (int jj = 0; jj < 4; jj++) {
                int kvv = t * 64 + g * 16 + ni * 4 + jj;
                if (kvv > q) sv[qf][ni][jj] = -3.0e38f;
              }
          }
        }

#pragma unroll
        for (int qf = 0; qf < 2; qf++) {
          float mx = sv[qf][0][0];
#pragma unroll
          for (int ni = 0; ni < 4; ni++)
#pragma unroll
            for (int jj = 0; jj < 4; jj++) mx = fmaxf(mx, sv[qf][ni][jj]);
          mx = fmaxf(mx, __shfl_xor(mx, 16));
          mx = fmaxf(mx, __shfl_xor(mx, 32));
          float mnew = fmaxf(m_run[qf], mx);
          float al = exp2f(m_run[qf] - mnew);
          m_run[qf] = mnew;
          float rs = 0.f;
#pragma unroll
          for (int ni = 0; ni < 4; ni++)
#pragma unroll
            for (int jj = 0; jj < 4; jj++) {
              float p = exp2f(sv[qf][ni][jj] - mnew);
              sv[qf][ni][jj] = p;
              rs += p;
            }
          rs += __shfl_xor(rs, 16);
          rs += __shfl_xor(rs, 32);
          l_run[qf] = l_run[qf] * al + rs;
#pragma unroll
          for (int nh = 0; nh < 4; nh++) acc[qf][nh] *= al;

          // P -> bf16 B-fragments, purely in-lane
          union { unsigned int u[4]; bf16x8 v; } pb0, pb1;
          pb0.u[0] = cvt_pk_bf16(sv[qf][0][0], sv[qf][0][1]);
          pb0.u[1] = cvt_pk_bf16(sv[qf][0][2], sv[qf][0][3]);
          pb0.u[2] = cvt_pk_bf16(sv[qf][1][0], sv[qf][1][1]);
          pb0.u[3] = cvt_pk_bf16(sv[qf][1][2], sv[qf][1][3]);
          pb1.u[0] = cvt_pk_bf16(sv[qf][2][0], sv[qf][2][1]);
          pb1.u[1] = cvt_pk_bf16(sv[qf][2][2], sv[qf][2][3]);
          pb1.u[2] = cvt_pk_bf16(sv[qf][3][0], sv[qf][3][1]);
          pb1.u[3] = cvt_pk_bf16(sv[qf][3][2], sv[qf][3][3]);

          __builtin_amdgcn_s_setprio(1);
#pragma unroll
          for (int nh = 0; nh < 4; nh++) {
            acc[qf][nh] = __builtin_amdgcn_mfma_f32_16x16x32_bf16(va[nh][0], pb0.v, acc[qf][nh], 0, 0, 0);
            acc[qf][nh] = __builtin_amdgcn_mfma_f32_16x16x32_bf16(va[nh][1], pb1.v, acc[qf][nh], 0, 0, 0);
          }
          __builtin_amdgcn_s_setprio(0);
        }
      }
      if (more) {   // write-late: next tile into the other buffer
        *(uint4*)&Klds[cur ^ 1][kdst] = knx;
        *(uint4*)&Vlds[cur ^ 1][vdst] = vnx;
        __syncthreads();
        cur ^= 1;
      }
    }

    // epilogue: ctx2d[b*S+q][h*64+hd] = acc/l ; hd = nh*16 + g*4 + jj
#pragma unroll
    for (int qf = 0; qf < 2; qf++) {
      float inv = 1.0f / l_run[qf];
      size_t rowoff = ((size_t)b * SS + q0 + qf * 16 + c) * DOUT + h * HD;
#pragma unroll
      for (int nh = 0; nh < 4; nh++) {
        uint2 st;
        st.x = cvt_pk_bf16(acc[qf][nh][0] * inv, acc[qf][nh][1] * inv);
        st.y = cvt_pk_bf16(acc[qf][nh][2] * inv, acc[qf][nh][3] * inv);
        *(uint2*)&ctx[rowoff + nh * 16 + g * 4] = st;
      }
    }
  }
}

// ---------------- launch ----------------

extern "C" void kernel_launch(void* const* d_in, const int* in_sizes, int n_in,
                              void* d_out, int out_size, void* d_ws, size_t ws_size,
                              hipStream_t stream) {
  const float* x  = (const float*)d_in[0];
  const float* Wq = (const float*)d_in[1];
  const float* Wk = (const float*)d_in[2];
  const float* Wv = (const float*)d_in[3];
  const float* Wp = (const float*)d_in[4];
  const float* bp = (const float*)d_in[5];
  float* out = (float*)d_out;

  unsigned short* ws = (unsigned short*)d_ws;
  unsigned short* xb = ws;                      // 8388608 elems (x bf16; later reused as ctx)
  unsigned short* wt = xb + (size_t)MROWS * DIN;       // 4 * 1048576 (Wq^T,Wk^T,Wv^T,Wp^T)
  unsigned short* qs = wt + (size_t)4 * DIN * DOUT;    // 8388608 (Q scaled, [b][h][s][hd])
  unsigned short* kb = qs + (size_t)MROWS * DOUT;      // 8388608 ([b][h][s][hd])
  unsigned short* vt = kb + (size_t)MROWS * DOUT;      // 8388608 ([b][h][hd][s])
  unsigned short* ctx = xb;                            // alias: x dead after projections

  cvt_x_kernel<<<4096, 256, 0, stream>>>(x, xb, (MROWS * DIN) / 4);
  cvt_w_t_kernel<<<dim3(32, 32, 4), dim3(32, 32), 0, stream>>>(Wq, Wk, Wv, Wp, wt);
  gemm_qkv_kernel<<<dim3(8, 64, 3), 256, 0, stream>>>(xb, wt, qs, kb, vt);
  attn_kernel<<<dim3(4, NH, BB), 512, 0, stream>>>(qs, kb, vt, ctx);
  gemm_out_kernel<<<dim3(8, 64), 256, 0, stream>>>(ctx, wt + (size_t)3 * DIN * DOUT, bp, out);
}